// Round 8
// baseline (287.070 us; speedup 1.0000x reference)
//
#include <hip/hip_runtime.h>

constexpr int NQ = 512;
constexpr int NKV = 512;
constexpr int Hh = 16;
constexpr int Dd = 256;

// C = A @ W^T + bias. M=4096, N=256, K=256. BM=BN=64, BK=64.
__global__ __launch_bounds__(256) void gemm_bias(
    const float* __restrict__ A, const float* __restrict__ W,
    const float* __restrict__ bias, float* __restrict__ C) {
  __shared__ float As[64][68];
  __shared__ float Ws[64][68];
  const int t = threadIdx.x;
  const int tx = t & 15, ty = t >> 4;
  const int m0 = blockIdx.x * 64, n0 = blockIdx.y * 64;

  float acc[4][4] = {};
  float4 av[4], wv[4];

#pragma unroll
  for (int i = 0; i < 4; ++i) {
    const int flat = i * 256 + t;
    const int r = flat >> 4, c4 = (flat & 15) << 2;
    av[i] = *(const float4*)(A + (size_t)(m0 + r) * 256 + c4);
    wv[i] = *(const float4*)(W + (size_t)(n0 + r) * 256 + c4);
  }

  for (int kb = 0; kb < 4; ++kb) {
#pragma unroll
    for (int i = 0; i < 4; ++i) {
      const int flat = i * 256 + t;
      const int r = flat >> 4, c4 = (flat & 15) << 2;
      As[c4 + 0][r] = av[i].x; As[c4 + 1][r] = av[i].y;
      As[c4 + 2][r] = av[i].z; As[c4 + 3][r] = av[i].w;
      Ws[c4 + 0][r] = wv[i].x; Ws[c4 + 1][r] = wv[i].y;
      Ws[c4 + 2][r] = wv[i].z; Ws[c4 + 3][r] = wv[i].w;
    }
    __syncthreads();
    if (kb < 3) {
#pragma unroll
      for (int i = 0; i < 4; ++i) {
        const int flat = i * 256 + t;
        const int r = flat >> 4, c4 = (flat & 15) << 2;
        av[i] = *(const float4*)(A + (size_t)(m0 + r) * 256 + (kb + 1) * 64 + c4);
        wv[i] = *(const float4*)(W + (size_t)(n0 + r) * 256 + (kb + 1) * 64 + c4);
      }
    }
#pragma unroll 16
    for (int k = 0; k < 64; ++k) {
      float a_[4], w_[4];
      *(float4*)a_ = *(const float4*)&As[k][ty << 2];
      *(float4*)w_ = *(const float4*)&Ws[k][tx << 2];
#pragma unroll
      for (int i = 0; i < 4; ++i)
#pragma unroll
        for (int j = 0; j < 4; ++j)
          acc[i][j] = fmaf(a_[i], w_[j], acc[i][j]);
    }
    if (kb < 3) __syncthreads();
  }

  const float4 bv = *(const float4*)(bias + n0 + (tx << 2));
  const float bb[4] = {bv.x, bv.y, bv.z, bv.w};
#pragma unroll
  for (int i = 0; i < 4; ++i) {
    float4 cv;
    cv.x = acc[i][0] + bb[0]; cv.y = acc[i][1] + bb[1];
    cv.z = acc[i][2] + bb[2]; cv.w = acc[i][3] + bb[3];
    *(float4*)(C + (size_t)(m0 + (ty << 2) + i) * 256 + n0 + (tx << 2)) = cv;
  }
}

// Fused masked softmax + per-head aggregation + L2 rescale. v9:
// v8's computation in QUARTER-SIZE workgroups: 256 thr = 4 waves = 4 octs,
// 2 q-rows per block, grid 256x8 = 2048 blocks, E dbuf = 10.2 KB ->
// 8 blocks/CU (wave-capped). Tests the occupancy hypothesis: all 512-thr
// variants pinned at ~41% occupancy (~2 blocks/CU) regardless of LDS;
// smaller independent blocks should let the CU interleave 8 of them and
// cover the P-load (L2/L3) stalls that leave VALUBusy at 28%.
// Oct assignment rotated by blockIdx.x so co-resident blocks read
// different 128-row P panels (spreads L2 bursts). No inline asm, unroll 1
// on loops, scalar-named accumulators: the proven no-spill recipe
// (WRITE_SIZE ~4 MB is the canary).
__global__ __launch_bounds__(256) void attn_fused(
    const float* __restrict__ msg, const int* __restrict__ adj,
    const float* __restrict__ proj, float* __restrict__ attn_out) {
  __shared__ float Esh[2][4][2][16][10];  // 10.24 KB: [buf][oct][q][h^q][k(8)+pad]

  const int t    = threadIdx.x;
  const int lane = t & 63;
  const int w    = t >> 6;              // wave 0..3
  const int bx   = blockIdx.x;
  const int oct  = (w + bx) & 3;        // rotated k-quarter for FMA
  const int h    = lane >> 2;
  const int d4   = lane & 3;
  const int col  = lane << 2;           // = h*16 + d4*4
  const int q0   = bx * 2;
  const int b    = blockIdx.y;

  // E-production decomposition: thread -> (h4, q, oct, k)
  const int p_h4  = t & 3;
  const int p_q   = (t >> 2) & 1;
  const int p_oct = (t >> 3) & 3;
  const int p_k   = t >> 5;             // 0..7 (k within oct's 8-row round)

  const float* mrow  = msg + ((size_t)(b * NQ + q0 + p_q) * NKV) * Hh + p_h4 * 4;
  const int*   arow  = adj + (size_t)(b * NQ + q0 + p_q) * NKV;
  const float* pbase = proj + (size_t)b * NKV * Dd;

  float4 o0 = {}, o1 = {};
  float s0 = 0.f, s1 = 0.f, r0 = 0.f, r1 = 0.f;

  float4 mv;
  int aa;

  // ---- prologue: msg(0) -> E(0) -> Esh[0]; sync ----
  {
    const int kg = p_oct * 128 + p_k;
    mv = *(const float4*)(mrow + (size_t)kg * Hh);
    aa = arow[kg];
    float e[4];
    e[0] = aa > 0 ? __expf(mv.x) : 0.f;
    e[1] = aa > 0 ? __expf(mv.y) : 0.f;
    e[2] = aa > 0 ? __expf(mv.z) : 0.f;
    e[3] = aa > 0 ? __expf(mv.w) : 0.f;
#pragma unroll
    for (int i = 0; i < 4; ++i)
      Esh[0][p_oct][p_q][(p_h4 * 4 + i) ^ p_q][p_k] = e[i];
  }
  __syncthreads();

#pragma unroll 1
  for (int rd = 0; rd < 16; ++rd) {
    const int cur = rd & 1, nxt = cur ^ 1;
    // msg(rd+1) prefetch: consumed after the FMA phase below.
    if (rd < 15) {
      const int kg = p_oct * 128 + (rd + 1) * 8 + p_k;
      mv = *(const float4*)(mrow + (size_t)kg * Hh);
      aa = arow[kg];
    }

    // ---- FMA(rd): 8 k-rows of this wave's oct; P from global (L2) ----
    __builtin_amdgcn_s_setprio(1);
#pragma unroll 1
    for (int kq = 0; kq < 2; ++kq) {
      const float* prow =
          pbase + (size_t)(oct * 128 + rd * 8 + kq * 4) * Dd + col;
      const float4 p0 = *(const float4*)(prow);
      const float4 p1 = *(const float4*)(prow + Dd);
      const float4 p2 = *(const float4*)(prow + 2 * Dd);
      const float4 p3 = *(const float4*)(prow + 3 * Dd);
      const float4 ea = *(const float4*)&Esh[cur][oct][0][h][kq * 4];
      const float4 eb = *(const float4*)&Esh[cur][oct][1][h ^ 1][kq * 4];
      s0 += ea.x + ea.y + ea.z + ea.w;
      r0 = fmaf(ea.x, ea.x, fmaf(ea.y, ea.y,
           fmaf(ea.z, ea.z, fmaf(ea.w, ea.w, r0))));
      o0.x = fmaf(ea.x, p0.x, o0.x); o0.y = fmaf(ea.x, p0.y, o0.y);
      o0.z = fmaf(ea.x, p0.z, o0.z); o0.w = fmaf(ea.x, p0.w, o0.w);
      o0.x = fmaf(ea.y, p1.x, o0.x); o0.y = fmaf(ea.y, p1.y, o0.y);
      o0.z = fmaf(ea.y, p1.z, o0.z); o0.w = fmaf(ea.y, p1.w, o0.w);
      o0.x = fmaf(ea.z, p2.x, o0.x); o0.y = fmaf(ea.z, p2.y, o0.y);
      o0.z = fmaf(ea.z, p2.z, o0.z); o0.w = fmaf(ea.z, p2.w, o0.w);
      o0.x = fmaf(ea.w, p3.x, o0.x); o0.y = fmaf(ea.w, p3.y, o0.y);
      o0.z = fmaf(ea.w, p3.z, o0.z); o0.w = fmaf(ea.w, p3.w, o0.w);
      s1 += eb.x + eb.y + eb.z + eb.w;
      r1 = fmaf(eb.x, eb.x, fmaf(eb.y, eb.y,
           fmaf(eb.z, eb.z, fmaf(eb.w, eb.w, r1))));
      o1.x = fmaf(eb.x, p0.x, o1.x); o1.y = fmaf(eb.x, p0.y, o1.y);
      o1.z = fmaf(eb.x, p0.z, o1.z); o1.w = fmaf(eb.x, p0.w, o1.w);
      o1.x = fmaf(eb.y, p1.x, o1.x); o1.y = fmaf(eb.y, p1.y, o1.y);
      o1.z = fmaf(eb.y, p1.z, o1.z); o1.w = fmaf(eb.y, p1.w, o1.w);
      o1.x = fmaf(eb.z, p2.x, o1.x); o1.y = fmaf(eb.z, p2.y, o1.y);
      o1.z = fmaf(eb.z, p2.z, o1.z); o1.w = fmaf(eb.z, p2.w, o1.w);
      o1.x = fmaf(eb.w, p3.x, o1.x); o1.y = fmaf(eb.w, p3.y, o1.y);
      o1.z = fmaf(eb.w, p3.z, o1.z); o1.w = fmaf(eb.w, p3.w, o1.w);
    }
    __builtin_amdgcn_s_setprio(0);

    // ---- E(rd+1) -> Esh[nxt] (WAR: its readers finished before sync(rd-1)) ----
    if (rd < 15) {
      float e[4];
      e[0] = aa > 0 ? __expf(mv.x) : 0.f;
      e[1] = aa > 0 ? __expf(mv.y) : 0.f;
      e[2] = aa > 0 ? __expf(mv.z) : 0.f;
      e[3] = aa > 0 ? __expf(mv.w) : 0.f;
#pragma unroll
      for (int i = 0; i < 4; ++i)
        Esh[nxt][p_oct][p_q][(p_h4 * 4 + i) ^ p_q][p_k] = e[i];
    }
    __syncthreads();  // publish Esh[nxt]; drains only the msg prefetch
  }

  // ---- epilogue: 4-wave tree-reduce (o,s,r) over the 4 octs ----
  float* base = &Esh[0][0][0][0][0];
  float4* Ro = (float4*)base;      // 4 regions x 64 lanes = 4 KB
  float*  Rs = base + 1024;        // 64 floats
  float*  Rr = base + 1088;        // 64 floats

  __syncthreads();
  if (w >= 2) {  // waves 2,3 -> regions (w-2)*2 + {0,1}
    const int reg = w - 2;
    Ro[(reg * 2 + 0) * 64 + lane] = o0;
    Ro[(reg * 2 + 1) * 64 + lane] = o1;
    if (d4 == 0) {
      Rs[(reg * 2 + 0) * 16 + h] = s0; Rs[(reg * 2 + 1) * 16 + h] = s1;
      Rr[(reg * 2 + 0) * 16 + h] = r0; Rr[(reg * 2 + 1) * 16 + h] = r1;
    }
  }
  __syncthreads();
  if (w < 2) {
    const float4 v0 = Ro[(w * 2 + 0) * 64 + lane];
    const float4 v1 = Ro[(w * 2 + 1) * 64 + lane];
    o0.x += v0.x; o0.y += v0.y; o0.z += v0.z; o0.w += v0.w;
    o1.x += v1.x; o1.y += v1.y; o1.z += v1.z; o1.w += v1.w;
    s0 += Rs[(w * 2 + 0) * 16 + h]; s1 += Rs[(w * 2 + 1) * 16 + h];
    r0 += Rr[(w * 2 + 0) * 16 + h]; r1 += Rr[(w * 2 + 1) * 16 + h];
  }
  __syncthreads();
  if (w == 1) {
    Ro[0 * 64 + lane] = o0;
    Ro[1 * 64 + lane] = o1;
    if (d4 == 0) {
      Rs[0 * 16 + h] = s0; Rs[1 * 16 + h] = s1;
      Rr[0 * 16 + h] = r0; Rr[1 * 16 + h] = r1;
    }
  }
  __syncthreads();
  if (w == 0) {
    const float4 v0 = Ro[0 * 64 + lane];
    const float4 v1 = Ro[1 * 64 + lane];
    o0.x += v0.x; o0.y += v0.y; o0.z += v0.z; o0.w += v0.w;
    o1.x += v1.x; o1.y += v1.y; o1.z += v1.z; o1.w += v1.w;
    const float st0 = s0 + Rs[0 * 16 + h];
    const float st1 = s1 + Rs[1 * 16 + h];
    const float rt0 = r0 + Rr[0 * 16 + h];
    const float rt1 = r1 + Rr[1 * 16 + h];
    const float wg0 = sqrtf(rt0) / (st0 * st0);
    const float wg1 = sqrtf(rt1) / (st1 * st1);
    float4 u0, u1;
    u0.x = o0.x * wg0; u0.y = o0.y * wg0; u0.z = o0.z * wg0; u0.w = o0.w * wg0;
    u1.x = o1.x * wg1; u1.y = o1.y * wg1; u1.z = o1.z * wg1; u1.w = o1.w * wg1;
    *(float4*)(attn_out + (size_t)(b * NQ + q0 + 0) * Dd + col) = u0;
    *(float4*)(attn_out + (size_t)(b * NQ + q0 + 1) * Dd + col) = u1;
  }
}

extern "C" void kernel_launch(void* const* d_in, const int* in_sizes, int n_in,
                              void* d_out, int out_size, void* d_ws, size_t ws_size,
                              hipStream_t stream) {
  const float* v_inv    = (const float*)d_in[0];
  const float* messages = (const float*)d_in[1];
  const int*   adj      = (const int*)d_in[2];
  const float* W_in     = (const float*)d_in[3];
  const float* b_in     = (const float*)d_in[4];
  const float* W_out    = (const float*)d_in[5];
  const float* b_out    = (const float*)d_in[6];
  float* out = (float*)d_out;

  float* proj = (float*)d_ws;                      // 4 MB [B,NKV,D]
  float* attn = proj + (size_t)8 * NKV * Dd;       // 4 MB [B,NQ,D]

  dim3 gg(64, 4);
  gemm_bias<<<gg, 256, 0, stream>>>(v_inv, W_in, b_in, proj);
  attn_fused<<<dim3(256, 8), 256, 0, stream>>>(messages, adj, proj, attn);
  gemm_bias<<<gg, 256, 0, stream>>>(attn, W_out, b_out, out);
}

// Round 9
// 250.899 us; speedup vs baseline: 1.1442x; 1.1442x over previous
//
#include <hip/hip_runtime.h>

constexpr int NQ = 512;
constexpr int NKV = 512;
constexpr int Hh = 16;
constexpr int Dd = 256;

// C = A @ W^T + bias. M=4096, N=256, K=256. BM=BN=64, BK=64.
// T14: next K-tile is prefetched into registers AFTER the publish barrier,
// so global latency hides under the 64-iter FMA loop (1 block/CU -> no
// cross-block cover; in-block pipelining is the only latency hiding).
__global__ __launch_bounds__(256) void gemm_bias(
    const float* __restrict__ A, const float* __restrict__ W,
    const float* __restrict__ bias, float* __restrict__ C) {
  __shared__ float As[64][68];
  __shared__ float Ws[64][68];
  const int t = threadIdx.x;
  const int tx = t & 15, ty = t >> 4;
  const int m0 = blockIdx.x * 64, n0 = blockIdx.y * 64;

  float acc[4][4] = {};
  float4 av[4], wv[4];

  // prologue: prefetch kb=0
#pragma unroll
  for (int i = 0; i < 4; ++i) {
    const int flat = i * 256 + t;
    const int r = flat >> 4, c4 = (flat & 15) << 2;
    av[i] = *(const float4*)(A + (size_t)(m0 + r) * 256 + c4);
    wv[i] = *(const float4*)(W + (size_t)(n0 + r) * 256 + c4);
  }

  for (int kb = 0; kb < 4; ++kb) {
    // write staged regs -> LDS (protected by previous round's end barrier)
#pragma unroll
    for (int i = 0; i < 4; ++i) {
      const int flat = i * 256 + t;
      const int r = flat >> 4, c4 = (flat & 15) << 2;
      As[c4 + 0][r] = av[i].x; As[c4 + 1][r] = av[i].y;
      As[c4 + 2][r] = av[i].z; As[c4 + 3][r] = av[i].w;
      Ws[c4 + 0][r] = wv[i].x; Ws[c4 + 1][r] = wv[i].y;
      Ws[c4 + 2][r] = wv[i].z; Ws[c4 + 3][r] = wv[i].w;
    }
    __syncthreads();
    // prefetch next K-tile; issued after the barrier so the loads stay
    // in flight across the whole FMA loop below.
    if (kb < 3) {
#pragma unroll
      for (int i = 0; i < 4; ++i) {
        const int flat = i * 256 + t;
        const int r = flat >> 4, c4 = (flat & 15) << 2;
        av[i] = *(const float4*)(A + (size_t)(m0 + r) * 256 + (kb + 1) * 64 + c4);
        wv[i] = *(const float4*)(W + (size_t)(n0 + r) * 256 + (kb + 1) * 64 + c4);
      }
    }
#pragma unroll 16
    for (int k = 0; k < 64; ++k) {
      float a_[4], w_[4];
      *(float4*)a_ = *(const float4*)&As[k][ty << 2];
      *(float4*)w_ = *(const float4*)&Ws[k][tx << 2];
#pragma unroll
      for (int i = 0; i < 4; ++i)
#pragma unroll
        for (int j = 0; j < 4; ++j)
          acc[i][j] = fmaf(a_[i], w_[j], acc[i][j]);
    }
    if (kb < 3) __syncthreads();
  }

  const float4 bv = *(const float4*)(bias + n0 + (tx << 2));
  const float bb[4] = {bv.x, bv.y, bv.z, bv.w};
#pragma unroll
  for (int i = 0; i < 4; ++i) {
    float4 cv;
    cv.x = acc[i][0] + bb[0]; cv.y = acc[i][1] + bb[1];
    cv.z = acc[i][2] + bb[2]; cv.w = acc[i][3] + bb[3];
    *(float4*)(C + (size_t)(m0 + (ty << 2) + i) * 256 + n0 + (tx << 2)) = cv;
  }
}

// Fused masked softmax + per-head aggregation + L2 rescale.
// Empirical best over 9 variants (attn ~64us, total 251.4us): P staged via
// async global_load_lds (wave-uniform LDS base + lane*16B, linear dest);
// messages/adj reg-prefetched one round ahead, issued AFTER the publish
// barrier so HBM latency hides under the FMA phase; s_setprio(1) around
// the FMA cluster. Two __syncthreads per round: #1 publishes P (vmcnt
// drain, mostly covered by E-compute) + E; #2 is the Psh WAR fence.
// Alternatives all lost: P-in-regs and asm-walled counted-vmcnt variants
// spill at the allocator's hard 64-VGPR tier (180-400 MB scratch traffic);
// E-dbuf/half-round and global-P variants add LDS+sync overhead (+14-36us).
__global__ __launch_bounds__(512, 4) void attn_fused(
    const float* __restrict__ msg, const int* __restrict__ adj,
    const float* __restrict__ proj, float* __restrict__ attn_out) {
  __shared__ float Psh[4][8][256];     // 32 KB: [oct][k][col]
  __shared__ float Esh[4][8][16][12];  // 24 KB: [oct][q][h^q][k(8 used)]

  const int t    = threadIdx.x;
  const int lane = t & 63;
  const int w    = t >> 6;      // wave 0..7
  const int oct  = w >> 1;      // k-quarter for phase2
  const int qh   = w & 1;       // q-half for phase2
  const int h    = lane >> 2;
  const int d4   = lane & 3;
  const int col  = lane << 2;   // = h*16 + d4*4
  const int q0   = blockIdx.x * 8;
  const int b    = blockIdx.y;

  // phase-1 decomposition
  const int p_h4  = t & 3;
  const int p_q   = (t >> 2) & 7;
  const int p_oct = (t >> 5) & 3;
  const int p_jp  = t >> 7;     // 0..3 (k-pair)

  const float* mrow = msg + ((size_t)(b * NQ + q0 + p_q) * NKV) * Hh + p_h4 * 4;
  const int*   arow = adj + (size_t)(b * NQ + q0 + p_q) * NKV;
  const float* pb   = proj + (size_t)b * NKV * Dd;

  float4 o[4] = {};
  float s[4] = {}, r[4] = {};

  // staging registers for messages/adj, one round ahead
  float4 mv0, mv1;
  int a0, a1;
  {
    const int kg = p_oct * 128 + p_jp * 2;
    mv0 = *(const float4*)(mrow + (size_t)kg * Hh);
    mv1 = *(const float4*)(mrow + (size_t)(kg + 1) * Hh);
    a0 = arow[kg]; a1 = arow[kg + 1];
  }

  for (int rd = 0; rd < 16; ++rd) {
    // ---- stage P: async global->LDS. Wave w stages k-row w of each oct.
#pragma unroll
    for (int i = 0; i < 4; ++i) {
      const float* g = pb + (size_t)(i * 128 + rd * 8 + w) * Dd + (lane << 2);
      __builtin_amdgcn_global_load_lds(
          (const __attribute__((address_space(1))) unsigned int*)g,
          (__attribute__((address_space(3))) unsigned int*)&Psh[i][w][0],
          16, 0, 0);
    }
    // ---- stage E from the prefetched regs (mask*exp, swizzled store) ----
    {
      float e0[4], e1[4];
      e0[0] = a0 > 0 ? __expf(mv0.x) : 0.f; e0[1] = a0 > 0 ? __expf(mv0.y) : 0.f;
      e0[2] = a0 > 0 ? __expf(mv0.z) : 0.f; e0[3] = a0 > 0 ? __expf(mv0.w) : 0.f;
      e1[0] = a1 > 0 ? __expf(mv1.x) : 0.f; e1[1] = a1 > 0 ? __expf(mv1.y) : 0.f;
      e1[2] = a1 > 0 ? __expf(mv1.z) : 0.f; e1[3] = a1 > 0 ? __expf(mv1.w) : 0.f;
#pragma unroll
      for (int i = 0; i < 4; ++i) {
        const int h2 = (p_h4 * 4 + i) ^ p_q;  // XOR swizzle
        *(float2*)&Esh[p_oct][p_q][h2][p_jp * 2] = make_float2(e0[i], e1[i]);
      }
    }
    __syncthreads();  // publishes P (vmcnt drain) + E for this round

    // ---- prefetch next round's msg/adj: issued post-barrier, lands
    //      during the FMA phase below ----
    if (rd < 15) {
      const int kg = p_oct * 128 + (rd + 1) * 8 + p_jp * 2;
      mv0 = *(const float4*)(mrow + (size_t)kg * Hh);
      mv1 = *(const float4*)(mrow + (size_t)(kg + 1) * Hh);
      a0 = arow[kg]; a1 = arow[kg + 1];
    }

    // ---- phase 2: accumulate over this round's 8 k of wave's quarter ----
    __builtin_amdgcn_s_setprio(1);
#pragma unroll
    for (int kh = 0; kh < 2; ++kh) {
      float4 p[4];
#pragma unroll
      for (int j = 0; j < 4; ++j)
        p[j] = *(const float4*)&Psh[oct][kh * 4 + j][col];
#pragma unroll
      for (int qi = 0; qi < 4; ++qi) {
        const int ql = qh * 4 + qi;
        const float4 e4 = *(const float4*)&Esh[oct][ql][h ^ ql][kh * 4];
        s[qi] += e4.x + e4.y + e4.z + e4.w;
        r[qi] = fmaf(e4.x, e4.x, fmaf(e4.y, e4.y,
                fmaf(e4.z, e4.z, fmaf(e4.w, e4.w, r[qi]))));
        o[qi].x = fmaf(e4.x, p[0].x, o[qi].x);
        o[qi].y = fmaf(e4.x, p[0].y, o[qi].y);
        o[qi].z = fmaf(e4.x, p[0].z, o[qi].z);
        o[qi].w = fmaf(e4.x, p[0].w, o[qi].w);
        o[qi].x = fmaf(e4.y, p[1].x, o[qi].x);
        o[qi].y = fmaf(e4.y, p[1].y, o[qi].y);
        o[qi].z = fmaf(e4.y, p[1].z, o[qi].z);
        o[qi].w = fmaf(e4.y, p[1].w, o[qi].w);
        o[qi].x = fmaf(e4.z, p[2].x, o[qi].x);
        o[qi].y = fmaf(e4.z, p[2].y, o[qi].y);
        o[qi].z = fmaf(e4.z, p[2].z, o[qi].z);
        o[qi].w = fmaf(e4.z, p[2].w, o[qi].w);
        o[qi].x = fmaf(e4.w, p[3].x, o[qi].x);
        o[qi].y = fmaf(e4.w, p[3].y, o[qi].y);
        o[qi].z = fmaf(e4.w, p[3].z, o[qi].z);
        o[qi].w = fmaf(e4.w, p[3].w, o[qi].w);
      }
    }
    __builtin_amdgcn_s_setprio(0);
    if (rd < 15) __syncthreads();  // protect LDS from next round's staging
  }

  // ---- epilogue: tree-reduce partial (o,s,r) over the 4 k-quarters ----
  float4* Ro = (float4*)&Psh[0][0][0];  // 16 KB used
  float*  Rs = &Esh[0][0][0][0];        // 256 floats
  float*  Rr = Rs + 256;                // 256 floats

  __syncthreads();
  if (w >= 4) {  // oct 2,3 write regions 0..3
    const int reg = w - 4;
#pragma unroll
    for (int qi = 0; qi < 4; ++qi) {
      Ro[(reg * 4 + qi) * 64 + lane] = o[qi];
      if (d4 == 0) {
        Rs[(reg * 4 + qi) * 16 + h] = s[qi];
        Rr[(reg * 4 + qi) * 16 + h] = r[qi];
      }
    }
  }
  __syncthreads();
  if (w < 4) {
#pragma unroll
    for (int qi = 0; qi < 4; ++qi) {
      const float4 v = Ro[(w * 4 + qi) * 64 + lane];
      o[qi].x += v.x; o[qi].y += v.y; o[qi].z += v.z; o[qi].w += v.w;
      s[qi] += Rs[(w * 4 + qi) * 16 + h];
      r[qi] += Rr[(w * 4 + qi) * 16 + h];
    }
  }
  __syncthreads();
  if (w == 2 || w == 3) {  // oct 1 writes regions 0,1
    const int reg = w - 2;
#pragma unroll
    for (int qi = 0; qi < 4; ++qi) {
      Ro[(reg * 4 + qi) * 64 + lane] = o[qi];
      if (d4 == 0) {
        Rs[(reg * 4 + qi) * 16 + h] = s[qi];
        Rr[(reg * 4 + qi) * 16 + h] = r[qi];
      }
    }
  }
  __syncthreads();
  if (w < 2) {
#pragma unroll
    for (int qi = 0; qi < 4; ++qi) {
      const float4 v = Ro[(w * 4 + qi) * 64 + lane];
      o[qi].x += v.x; o[qi].y += v.y; o[qi].z += v.z; o[qi].w += v.w;
      const float st = s[qi] + Rs[(w * 4 + qi) * 16 + h];
      const float rt = r[qi] + Rr[(w * 4 + qi) * 16 + h];
      const float wgt = sqrtf(rt) / (st * st);
      float4 u;
      u.x = o[qi].x * wgt; u.y = o[qi].y * wgt;
      u.z = o[qi].z * wgt; u.w = o[qi].w * wgt;
      const int q = q0 + w * 4 + qi;
      *(float4*)(attn_out + (size_t)(b * NQ + q) * Dd + col) = u;
    }
  }
}

extern "C" void kernel_launch(void* const* d_in, const int* in_sizes, int n_in,
                              void* d_out, int out_size, void* d_ws, size_t ws_size,
                              hipStream_t stream) {
  const float* v_inv    = (const float*)d_in[0];
  const float* messages = (const float*)d_in[1];
  const int*   adj      = (const int*)d_in[2];
  const float* W_in     = (const float*)d_in[3];
  const float* b_in     = (const float*)d_in[4];
  const float* W_out    = (const float*)d_in[5];
  const float* b_out    = (const float*)d_in[6];
  float* out = (float*)d_out;

  float* proj = (float*)d_ws;                      // 4 MB [B,NKV,D]
  float* attn = proj + (size_t)8 * NKV * Dd;       // 4 MB [B,NQ,D]

  dim3 gg(64, 4);
  gemm_bias<<<gg, 256, 0, stream>>>(v_inv, W_in, b_in, proj);
  attn_fused<<<dim3(64, 8), 512, 0, stream>>>(messages, adj, proj, attn);
  gemm_bias<<<gg, 256, 0, stream>>>(attn, W_out, b_out, out);
}